// Round 8
// baseline (262.016 us; speedup 1.0000x reference)
//
#include <hip/hip_runtime.h>

// BrickVectorEdgeModel on MI355X (gfx950).
// R15: edge -> 32x32x16 MFMA. Evidence: wall-edge gap ~90-107us is
// INSENSITIVE to node structure (R0/R10/R11/R13/R14) => fixed harness
// overhead + ~25us of small kernels; only lever left is edge (157us vs
// 75us 16x16-MFMA floor). 32x32x16 runs 2495 vs 2075 TF (m119/m06) and
// halves MFMA instr count -> floor 62us, denser pipe bursts per ds_read.
// Edge tile 144->128 rows (2i x 64j), 1152 blocks, LDS 141KB, 8 waves.
// Wcb/Wcc prep-tiled as 32col x 16k 1KB frags (wtile_off32); A: m=lane&31,
// k=(lane>>5)*8+e; C/D per guide (col=lane&31, row=(reg&3)+8*(reg>>2)+
// 4*(lane>>5)). Final Wout phase stays 16x16. Nodes/prep = R14 (best).
// 16x16 tiled W layout (nodes): off(c,k) =
//   ((c>>4)*16 + (k>>5))*512 + (c&15)*32 + (k&31)

typedef short  short8  __attribute__((ext_vector_type(8)));
typedef short  short4v __attribute__((ext_vector_type(4)));
typedef float  f32x4   __attribute__((ext_vector_type(4)));
typedef float  f32x16  __attribute__((ext_vector_type(16)));

#define LDSW 520   // LDS row stride in bf16 elems (520*2B = 1040B, 16B-aligned)

__device__ inline unsigned short f2bf(float x) {
  unsigned u = __float_as_uint(x);
  unsigned r = (u + 0x7FFFu + ((u >> 16) & 1u)) >> 16;  // RNE
  return (unsigned short)r;
}

__device__ __host__ inline int wtile_off(int c, int k) {
  return ((c >> 4) * 16 + (k >> 5)) * 512 + (c & 15) * 32 + (k & 31);
}
// 32x32x16 A-operand tiling: per (32-col tile ct, 16-k step ks) a contiguous
// 1KB fragment; within: elem (c&31)*16 + (k&15). Lane (c=lane&31,kg=lane>>5)
// reads 16B at (c&31)*16 + kg*8 -> wave covers the 1KB exactly (coalesced).
__device__ __host__ inline int wtile_off32(int c, int k) {
  return ((c >> 5) * 32 + (k >> 4)) * 512 + (c & 31) * 16 + (k & 15);
}

template <int MT, int NT>
__device__ inline void zero_acc(f32x4 (&acc)[MT][NT]) {
#pragma unroll
  for (int mt = 0; mt < MT; ++mt)
#pragma unroll
    for (int nt = 0; nt < NT; ++nt) {
      f32x4 z = {0.f, 0.f, 0.f, 0.f};
      acc[mt][nt] = z;
    }
}

template <int MT, int NT>
__device__ inline void zero_acc32(f32x16 (&acc)[MT][NT]) {
#pragma unroll
  for (int mt = 0; mt < MT; ++mt)
#pragma unroll
    for (int nt = 0; nt < NT; ++nt) {
      f32x16 z = {};
      acc[mt][nt] = z;
    }
}

// ---- 16x16x32 kloop (node layers; R7-proven) ----
template <int MT, int NT>
__device__ inline void gemm_kloop(const short* E, const short* __restrict__ W,
                                  int lane, int nbase, f32x4 (&acc)[MT][NT]) {
  const int mrow = lane & 15, kg = lane >> 4;
  const short* El = E + mrow * LDSW + kg * 8;
  const short* Wl = W + (nbase >> 4) * 8192 + mrow * 32 + kg * 8;
  short8 wF[2][NT];
#pragma unroll
  for (int nt = 0; nt < NT; ++nt) wF[0][nt] = *(const short8*)(Wl + nt * 8192);
#pragma unroll
  for (int ks = 0; ks < 16; ++ks) {
    const int cur = ks & 1, nxt = cur ^ 1;
    if (ks < 15) {
      const int k1 = (ks + 1) * 512;
#pragma unroll
      for (int nt = 0; nt < NT; ++nt)
        wF[nxt][nt] = *(const short8*)(Wl + nt * 8192 + k1);
    }
    const int k0 = ks * 32;
    short8 e0 = *(const short8*)(El + k0);
#pragma unroll
    for (int mt = 0; mt < MT; ++mt) {
      const short8 ecur = e0;
      if (mt < MT - 1) e0 = *(const short8*)(El + (mt + 1) * 16 * LDSW + k0);
#pragma unroll
      for (int nt = 0; nt < NT; ++nt)
        acc[mt][nt] = __builtin_amdgcn_mfma_f32_16x16x32_bf16(
            wF[cur][nt], ecur, acc[mt][nt], 0, 0, 0);
    }
  }
}

// ---- 32x32x16 kloop (edge cb/cc layers) ----
// W as A (m = out-col): m=lane&31, k=(lane>>5)*8+e, from wtile_off32 frags.
// E as B (n = edge-row): n=lane&31, same k split, from LDS.
// W reg double-buffered across the 32 k-steps; E JIT 1-deep across mt.
template <int MT, int NT>
__device__ inline void gemm_kloop32(const short* E, const short* __restrict__ W,
                                    int lane, int nbase, f32x16 (&acc)[MT][NT]) {
  const int er = lane & 31, kg = lane >> 5;
  const short* El = E + er * LDSW + kg * 8;
  const short* Wl = W + (nbase >> 5) * 16384 + er * 16 + kg * 8;
  short8 wF[2][NT];
#pragma unroll
  for (int nt = 0; nt < NT; ++nt) wF[0][nt] = *(const short8*)(Wl + nt * 16384);
#pragma unroll
  for (int ks = 0; ks < 32; ++ks) {
    const int cur = ks & 1, nxt = cur ^ 1;
    if (ks < 31) {
      const int k1 = (ks + 1) * 512;
#pragma unroll
      for (int nt = 0; nt < NT; ++nt)
        wF[nxt][nt] = *(const short8*)(Wl + nt * 16384 + k1);
    }
    const int k0 = ks * 16;
    short8 e0 = *(const short8*)(El + k0);
#pragma unroll
    for (int mt = 0; mt < MT; ++mt) {
      const short8 ecur = e0;
      if (mt < MT - 1) e0 = *(const short8*)(El + (mt + 1) * 32 * LDSW + k0);
#pragma unroll
      for (int nt = 0; nt < NT; ++nt)
        acc[mt][nt] = __builtin_amdgcn_mfma_f32_32x32x16_bf16(
            wF[cur][nt], ecur, acc[mt][nt], 0, 0, 0);
    }
  }
}

// relu(acc + bias) -> bf16 -> LDS (16x16 C/D layout; node path unused here,
// edge final no longer uses this, kept for symmetry with nodes).
template <int MT, int NT>
__device__ inline void store_relu_lds(short* E, const float* __restrict__ bias,
                                      int lane, int nbase, f32x4 (&acc)[MT][NT]) {
  const int mrow = lane & 15, kg = lane >> 4;
#pragma unroll
  for (int nt = 0; nt < NT; ++nt) {
    const int oc = nbase + nt * 16 + kg * 4;
    const float4 bs = *(const float4*)(bias + oc);
#pragma unroll
    for (int mt = 0; mt < MT; ++mt) {
      short4v s;
      s.x = (short)f2bf(fmaxf(acc[mt][nt][0] + bs.x, 0.f));
      s.y = (short)f2bf(fmaxf(acc[mt][nt][1] + bs.y, 0.f));
      s.z = (short)f2bf(fmaxf(acc[mt][nt][2] + bs.z, 0.f));
      s.w = (short)f2bf(fmaxf(acc[mt][nt][3] + bs.w, 0.f));
      *(short4v*)&E[(mt * 16 + mrow) * LDSW + oc] = s;
    }
  }
}

// relu(acc + bias) -> bf16 -> LDS for 32x32 C/D layout:
// edge-row = lane&31, out-col = (reg&3) + 8*(reg>>2) + 4*(lane>>5).
template <int MT, int NT>
__device__ inline void store_relu_lds32(short* E, const float* __restrict__ bias,
                                        int lane, int nbase, f32x16 (&acc)[MT][NT]) {
  const int er = lane & 31, kh = lane >> 5;
#pragma unroll
  for (int nt = 0; nt < NT; ++nt) {
#pragma unroll
    for (int rg = 0; rg < 4; ++rg) {
      const int oc = nbase + nt * 32 + rg * 8 + kh * 4;
      const float4 bs = *(const float4*)(bias + oc);
#pragma unroll
      for (int mt = 0; mt < MT; ++mt) {
        short4v s;
        s.x = (short)f2bf(fmaxf(acc[mt][nt][rg * 4 + 0] + bs.x, 0.f));
        s.y = (short)f2bf(fmaxf(acc[mt][nt][rg * 4 + 1] + bs.y, 0.f));
        s.z = (short)f2bf(fmaxf(acc[mt][nt][rg * 4 + 2] + bs.z, 0.f));
        s.w = (short)f2bf(fmaxf(acc[mt][nt][rg * 4 + 3] + bs.w, 0.f));
        *(short4v*)&E[(mt * 32 + er) * LDSW + oc] = s;
      }
    }
  }
}

// ---------------- prep: fp32 -> bf16 + tiled relayout ----------------
// Wa/Wb/Wuv in 16x16 tiling (nodes); Wcb/Wcc in 32x32 tiling (edge);
// Wout plain row-major.
__global__ void prep_kernel(const float* __restrict__ Wa, const float* __restrict__ Wb,
                            const float* __restrict__ Wca, const float* __restrict__ Wcb,
                            const float* __restrict__ Wcc, const float* __restrict__ Wout,
                            short* __restrict__ outS) {
  const int tid = blockIdx.x * blockDim.x + threadIdx.x;
  const int stride = gridDim.x * blockDim.x;
  const int M = 262144;
  for (int i = tid; i < 6 * M + 1024; i += stride) {
    float x;
    int dst;
    if (i < M) {                       // WaB tiled16
      const int c = i >> 9, k = i & 511;
      x = Wa[i];
      dst = wtile_off(c, k);
    } else if (i < 2 * M) {            // WbB tiled16
      const int t = i - M, c = t >> 9, k = t & 511;
      x = Wb[t];
      dst = M + wtile_off(c, k);
    } else if (i < 3 * M) {            // Wuv: u-half, tiled16 cols 0..511
      const int t = i - 2 * M, c = t >> 9, k = t & 511;
      x = Wca[c * 1024 + k];
      dst = 2 * M + wtile_off(c, k);
    } else if (i < 4 * M) {            // Wuv: v-half, tiled16 cols 512..1023
      const int t = i - 3 * M, c = t >> 9, k = t & 511;
      x = Wca[c * 1024 + 512 + k];
      dst = 2 * M + wtile_off(512 + c, k);
    } else if (i < 5 * M) {            // WcbB tiled32 (edge)
      const int t = i - 4 * M, c = t >> 9, k = t & 511;
      x = Wcb[t];
      dst = 4 * M + wtile_off32(c, k);
    } else if (i < 6 * M) {            // WccB tiled32 (edge)
      const int t = i - 5 * M, c = t >> 9, k = t & 511;
      x = Wcc[t];
      dst = 5 * M + wtile_off32(c, k);
    } else {                           // Wout plain row-major
      x = Wout[i - 6 * M];
      dst = i;
    }
    outS[dst] = (short)f2bf(x);
  }
}

// ---------------- node stage: 3 per-layer tiled kernels (16 rows x 64 cols) --
// R14-proven: grids 384/384/768 fill all 256 CUs, ~6 resident blocks/CU.
template <int MODE>
__global__ __launch_bounds__(256, 4) void node_layer(
    const void* __restrict__ Xin, const short* __restrict__ W,
    const float* __restrict__ bias, const float* __restrict__ xy,
    const float* __restrict__ Wxy, const float* __restrict__ bxy,
    void* __restrict__ Yout, float* __restrict__ vout, int colTiles) {
  __shared__ short X[16 * LDSW];
  __shared__ float xyl[32];
  const int tid = threadIdx.x, lane = tid & 63, wave = tid >> 6;
  const int rt = blockIdx.x / colTiles, ct = blockIdx.x % colTiles;
  const int row0 = rt * 16, c0 = ct * 64;

  if (MODE == 1) {
    const float* bv = (const float*)Xin;
    const int hc = (tid & 127) * 4, m0 = tid >> 7;
    for (int m = m0; m < 16; m += 2) {
      const float4 t = *(const float4*)(bv + (row0 + m) * 512 + hc);
      short4v s;
      s.x = (short)f2bf(t.x); s.y = (short)f2bf(t.y);
      s.z = (short)f2bf(t.z); s.w = (short)f2bf(t.w);
      *(short4v*)&X[m * LDSW + hc] = s;
    }
    if (tid < 32) xyl[tid] = xy[row0 * 2 + tid];
  } else {
    const short* xb = (const short*)Xin;
    const int hc = (tid & 63) * 8, m0 = tid >> 6;
    for (int m = m0; m < 16; m += 4)
      *(short8*)&X[m * LDSW + hc] = *(const short8*)(xb + (row0 + m) * 512 + hc);
  }
  __syncthreads();

  const int nbase = c0 + wave * 16;
  f32x4 acc[1][1];
  zero_acc<1, 1>(acc);
  gemm_kloop<1, 1>(X, W, lane, nbase, acc);

  const int mrow = lane & 15, kg = lane >> 4;
  const int oc = nbase + kg * 4;
  if (MODE == 3) {
    float* u = (float*)Yout;
    const int row = row0 + mrow;
    if (oc < 512) *(f32x4*)&u[row * 512 + oc] = acc[0][0];     // block-uniform branch
    else          *(f32x4*)&vout[row * 512 + oc - 512] = acc[0][0];
  } else {
    short* Y = (short*)Yout;
    const float4 bs = *(const float4*)(bias + oc);
    float b2[4] = {0.f, 0.f, 0.f, 0.f}, w0[4], w1[4];
    if (MODE == 1) {
      const float4 t = *(const float4*)(bxy + oc);
      b2[0] = t.x; b2[1] = t.y; b2[2] = t.z; b2[3] = t.w;
#pragma unroll
      for (int r = 0; r < 4; ++r) { w0[r] = Wxy[(oc + r) * 2]; w1[r] = Wxy[(oc + r) * 2 + 1]; }
    }
    const int row = mrow;
    short4v s;
#pragma unroll
    for (int r = 0; r < 4; ++r) {
      float xv = acc[0][0][r] + ((const float*)&bs)[r];
      if (MODE == 1) xv += b2[r] + xyl[row * 2] * w0[r] + xyl[row * 2 + 1] * w1[r];
      ((short*)&s)[r] = (short)f2bf(fmaxf(xv, 0.f));
    }
    *(short4v*)&Y[(row0 + row) * 512 + oc] = s;
  }
}

// ---------------- edge stage: fused E0 -> E1 -> E2 -> out, 32x32 MFMA -----
// 128-row tiles (2 i x 64 j): LDS 141,312 B -> 1 block/CU, 8 waves.
// 1152 blocks = 4.5 rounds of 256 CUs. Per wave: 4 row-tiles x 2 col-tiles,
// acc[4][2] f32x16 = 128 VGPR; 8 independent 32x32 MFMAs per k-step.
__global__ __launch_bounds__(512, 2) void edge_kernel(
    const float* __restrict__ u, const float* __restrict__ v,
    const short* __restrict__ Wcb, const short* __restrict__ Wcc,
    const short* __restrict__ Wout,
    const float* __restrict__ bca, const float* __restrict__ bcb,
    const float* __restrict__ bcc, const float* __restrict__ bout,
    float* __restrict__ out) {
  __shared__ short A[128 * LDSW];      // 133,120 B
  __shared__ float red[128 * 2 * 8];   //   8,192 B
  const int tid = threadIdx.x, lane = tid & 63, wave = tid >> 6;
  const int blk = blockIdx.x;
  const int b = blk / 288, rem = blk % 288, ip = rem / 3, jt = rem % 3;
  const float* urow0 = u + (b * 192 + jt * 64) * 512;  // row m: j = jt*64 + (m&63)
  const float* vrow0 = v + (b * 192 + ip * 2) * 512;   // row m: i = ip*2 + (m>>6)

  {  // Phase 0: E0 = relu(u[j] + v[i] + b_ca) -> bf16 LDS
    const int hc = (tid & 127) * 4, m0 = tid >> 7;
    const float4 v0 = *(const float4*)(vrow0 + hc);
    const float4 v1 = *(const float4*)(vrow0 + 512 + hc);
    const float4 bb = *(const float4*)(bca + hc);
#pragma unroll 4
    for (int m = m0; m < 128; m += 4) {
      const float4 vv = (m >= 64) ? v1 : v0;
      const float4 uu = *(const float4*)(urow0 + (m & 63) * 512 + hc);
      short4v s;
      s.x = (short)f2bf(fmaxf(uu.x + vv.x + bb.x, 0.f));
      s.y = (short)f2bf(fmaxf(uu.y + vv.y + bb.y, 0.f));
      s.z = (short)f2bf(fmaxf(uu.z + vv.z + bb.z, 0.f));
      s.w = (short)f2bf(fmaxf(uu.w + vv.w + bb.w, 0.f));
      *(short4v*)&A[m * LDSW + hc] = s;
    }
  }
  __syncthreads();

  const int nbase = wave * 64;
  f32x16 acc[4][2];

  // layer cb
  zero_acc32<4, 2>(acc);
  gemm_kloop32<4, 2>(A, Wcb, lane, nbase, acc);
  __syncthreads();                 // all waves done reading E0
  store_relu_lds32<4, 2>(A, bcb, lane, nbase, acc);
  __syncthreads();

  // layer cc
  zero_acc32<4, 2>(acc);
  gemm_kloop32<4, 2>(A, Wcc, lane, nbase, acc);
  __syncthreads();
  store_relu_lds32<4, 2>(A, bcc, lane, nbase, acc);
  __syncthreads();

  // final: out = E2 @ Wout^T + bout.  16x16 path, k-split across 8 waves,
  // n padded 2->16, 8 row-tiles of 16.
  f32x4 oacc[8];
#pragma unroll
  for (int mt = 0; mt < 8; ++mt) { f32x4 z = {0.f, 0.f, 0.f, 0.f}; oacc[mt] = z; }
  const int n = lane & 15, kg2 = lane >> 4;
#pragma unroll
  for (int kk = 0; kk < 2; ++kk) {
    const int k0 = wave * 64 + kk * 32 + kg2 * 8;
    short8 bf = {0, 0, 0, 0, 0, 0, 0, 0};
    if (n < 2) bf = *(const short8*)(Wout + n * 512 + k0);
#pragma unroll
    for (int mt = 0; mt < 8; ++mt) {
      const short8 af = *(const short8*)(A + (mt * 16 + n) * LDSW + k0);
      oacc[mt] = __builtin_amdgcn_mfma_f32_16x16x32_bf16(af, bf, oacc[mt], 0, 0, 0);
    }
  }
  if (n < 2) {
#pragma unroll
    for (int mt = 0; mt < 8; ++mt)
#pragma unroll
      for (int r = 0; r < 4; ++r) {
        const int row = mt * 16 + kg2 * 4 + r;
        red[(row * 2 + n) * 8 + wave] = oacc[mt][r];
      }
  }
  __syncthreads();
  if (tid < 256) {
    const int row = tid >> 1, o = tid & 1;
    float s = bout[o];
#pragma unroll
    for (int w = 0; w < 8; ++w) s += red[(row * 2 + o) * 8 + w];
    const int ii = row >> 6, jj = row & 63;
    out[((b * 192 + ip * 2 + ii) * 192 + jt * 64 + jj) * 2 + o] = s;
  }
}

extern "C" void kernel_launch(void* const* d_in, const int* in_sizes, int n_in,
                              void* d_out, int out_size, void* d_ws, size_t ws_size,
                              hipStream_t stream) {
  const float* bv   = (const float*)d_in[0];
  const float* xy   = (const float*)d_in[1];
  const float* Wxy  = (const float*)d_in[2];
  const float* bxy  = (const float*)d_in[3];
  const float* Wa   = (const float*)d_in[4];
  const float* ba   = (const float*)d_in[5];
  const float* Wb   = (const float*)d_in[6];
  const float* bb   = (const float*)d_in[7];
  const float* Wca  = (const float*)d_in[8];
  const float* bca  = (const float*)d_in[9];
  const float* Wcb  = (const float*)d_in[10];
  const float* bcb  = (const float*)d_in[11];
  const float* Wcc  = (const float*)d_in[12];
  const float* bcc  = (const float*)d_in[13];
  const float* Wout = (const float*)d_in[14];
  const float* bout = (const float*)d_in[15];
  float* out = (float*)d_out;

  // ws layout (bytes): [0, 3,147,776) bf16 weights (tiled layout);
  // f1 bf16 @3,147,776 (aliased by u fp32, f1 dead before L3 writes u);
  // f2 bf16 @4,720,640; v fp32 @5,507,072; end 7,079,936.
  short* S = (short*)d_ws;
  char* base = (char*)d_ws;
  short* WaB   = S;
  short* WbB   = S + 262144;
  short* WuvB  = S + 524288;    // tiled16, 1024 cols: ct 0-31 = W1 (u), 32-63 = W2 (v)
  short* WcbB  = S + 1048576;   // tiled32
  short* WccB  = S + 1310720;   // tiled32
  short* WoutB = S + 1572864;
  short* f1 = (short*)(base + 3147776);
  float* u  = (float*)(base + 3147776);
  short* f2 = (short*)(base + 4720640);
  float* v  = (float*)(base + 5507072);

  prep_kernel<<<512, 256, 0, stream>>>(Wa, Wb, Wca, Wcb, Wcc, Wout, S);
  node_layer<1><<<384, 256, 0, stream>>>(bv, WaB, ba, xy, Wxy, bxy, f1, nullptr, 8);
  node_layer<2><<<384, 256, 0, stream>>>(f1, WbB, bb, nullptr, nullptr, nullptr, f2, nullptr, 8);
  node_layer<3><<<768, 256, 0, stream>>>(f2, WuvB, nullptr, nullptr, nullptr, nullptr, u, v, 16);
  edge_kernel<<<1152, 512, 0, stream>>>(u, v, WcbB, WccB, WoutB, bca, bcb, bcc, bout, out);
}